// Round 8
// baseline (1726.325 us; speedup 1.0000x reference)
//
#include <hip/hip_runtime.h>
#include <math.h>

#define HID 256
#define TWOH 512
#define ROWS 8192   // B*S
#define NLAYER 4
#define TMAX 50
#define DT 0.05f
#define EPSC 1e-3f
#define BROW 16     // rows per block (R7 had 32)

typedef float f32x4 __attribute__((ext_vector_type(4)));
typedef long  long2v __attribute__((ext_vector_type(2)));
typedef unsigned char u8;

// fp8 helpers (OCP e4m3 on gfx950)
__device__ inline u8 f32_to_fp8(float v) {
    return (u8)(__builtin_amdgcn_cvt_pk_fp8_f32(v, v, 0, 0) & 0xff);
}
__device__ inline float fp8_to_f32(u8 b) {
    return __builtin_amdgcn_cvt_f32_fp8((int)b, 0);
}

// ---------------------------------------------------------------------------
// Pair-packed fragment-major fp8 weights (UNCHANGED layout from R7 -- the
// stream is a function of (L, wv, ci, g) only, independent of block M).
//   g=0 -> tau columns, g=1 -> forcing columns; col d = wv*32 + h*16 + l15
//   k = ci*32 + quad*8 + j
// e bits: j:0-2, h:3, lane:4-9, g:10, ci:11-14, wv:15-17, L:18-19.
// tau row d: Wt[d][k]; forcing row d: k<256 ? Wi[d][k] : Ws[d][k-256].
// ---------------------------------------------------------------------------
__global__ void pack_w_kernel(const float* __restrict__ Ws,
                              const float* __restrict__ Wi,
                              const float* __restrict__ Wt,
                              u8* __restrict__ Wf) {
    int e = blockIdx.x * 256 + threadIdx.x;     // [0, 2^20)
    int j    = e & 7;
    int h    = (e >> 3) & 1;
    int lane = (e >> 4) & 63;
    int g    = (e >> 10) & 1;
    int ci   = (e >> 11) & 15;
    int wv   = (e >> 15) & 7;
    int L    = (e >> 18);
    int l15  = lane & 15;
    int quad = lane >> 4;
    int d = wv * 32 + h * 16 + l15;
    int k = ci * 32 + quad * 8 + j;
    float v;
    if (g == 0) {
        v = Wt[(size_t)L * HID * TWOH + (size_t)d * TWOH + k];
    } else {
        v = (k < HID) ? Wi[(size_t)L * HID * HID + (size_t)d * HID + k]
                      : Ws[(size_t)L * HID * HID + (size_t)d * HID + (k - HID)];
    }
    Wf[e] = f32_to_fp8(v);
}

__global__ void pack_b_kernel(const float* __restrict__ bs,
                              const float* __restrict__ bi,
                              const float* __restrict__ bt,
                              float* __restrict__ bp) {
    int idx = blockIdx.x * 256 + threadIdx.x;   // [0, 4*512): L*512 + n
    int L = idx / TWOH;
    int n = idx % TWOH;
    int d = n >> 1;
    bp[idx] = ((n & 1) == 0) ? bt[L * HID + d]
                             : (bs[L * HID + d] + bi[L * HID + d]);
}

// ---------------------------------------------------------------------------
// Persistent kernel: 512 blocks x 512 threads, block owns BROW=16 rows.
// 8 waves, one 32-d col-group each; every wave computes ONE 16-row tile
// (acc[4] = 16 regs, halved vs R7).
//
// Why 16-row blocks: R7 (256 blocks x 32 rows, 80 KB LDS) ran 1 block/CU =
// 2 waves/SIMD; profile showed ~33% MFMA + ~7% VALU + ~60% stall -- latency
// unhidden at 2 waves in barrier lockstep. Here LDS = 44 KB/block -> TWO
// independent blocks/CU (4 waves/SIMD) with no shared barriers; their skew
// hides ds_read/L2/epilogue latency. Cost: weight stream doubles chip-wide
// (~128 MB/stage from L2, ~3.7us/stage floor) -- acceptable vs the stall.
//
// Stage structure (R7, kept): h double-buffered; upper-K (ci 8..15, A=h_prev)
// | barrier | lower-K (ci 0..7, A=cur_in) | epilogue, no end barrier.
// #pragma unroll 1 on t and L loops (R6 lesson: cross-stage static overlap
// -> live-range blowup -> spill; verified fixed in R7, FETCH 8.3 MB).
// ---------------------------------------------------------------------------
__global__ __launch_bounds__(512, 1) void persistent_kernel(
    const float* __restrict__ x,
    const u8* __restrict__ Wf,
    const float* __restrict__ bp,
    float* __restrict__ deltas,
    float* __restrict__ out)
{
    __shared__ u8 sX[BROW * 256];                 //  4 KB
    __shared__ u8 sH[2][NLAYER][BROW * 256];      // 32 KB (double-buffered)
    __shared__ float2 sBias[NLAYER][256];         //  8 KB (b_tau, b_forcing)

    const int tid  = threadIdx.x;
    const int lane = tid & 63;
    const int wv   = tid >> 6;               // 0..7 col group (d-base wv*32)
    const int l15  = lane & 15;
    const int quad = lane >> 4;              // 0..3
    const int w32  = wv * 32;
    const size_t rowbase = (size_t)blockIdx.x * BROW;

    // ---- stage x -> sX (fp8, swizzled): 16 rows x 32 segs = 512 units ----
    {
        int r = tid >> 5, seg = tid & 31;
        const float* gx = x + (rowbase + r) * HID + seg * 8;
        float4 v0 = *(const float4*)gx;
        float4 v1 = *(const float4*)(gx + 4);
        int lo = __builtin_amdgcn_cvt_pk_fp8_f32(v0.x, v0.y, 0, 0);
        lo     = __builtin_amdgcn_cvt_pk_fp8_f32(v0.z, v0.w, lo, 1);
        int hi = __builtin_amdgcn_cvt_pk_fp8_f32(v1.x, v1.y, 0, 0);
        hi     = __builtin_amdgcn_cvt_pk_fp8_f32(v1.z, v1.w, hi, 1);
        long pk = ((long)(unsigned int)lo) | ((long)hi << 32);
        *(long*)&sX[r * 256 + (seg ^ r) * 8] = pk;
    }
    // ---- zero both h buffers: 32 KB = 4096 longs ----
    {
        long* hflat = (long*)&sH[0][0][0];
        #pragma unroll
        for (int it = 0; it < 8; ++it) hflat[tid + it * 512] = 0;
    }
    // ---- bias table -> LDS: 1024 entries ----
    #pragma unroll
    for (int it = 0; it < 2; ++it) {
        int i = tid + it * 512;
        sBias[i >> 8][i & 255] = *(const float2*)(bp + (i >> 8) * TWOH + 2 * (i & 255));
    }

    __syncthreads();

    #pragma unroll 1
    for (int t = 0; t < TMAX; ++t) {
        const int rs = t & 1, ws = rs ^ 1;
        #pragma unroll 1
        for (int L = 0; L < NLAYER; ++L) {
            const u8* Ahi = &sH[rs][L][0];                      // h_prev (k>=256)
            const u8* Alo = (L == 0) ? sX : &sH[ws][L - 1][0];  // cur_in (k<256)
            u8*       Hout = &sH[ws][L][0];
            // wave's pair-fragment stream: 32 KB contiguous per (L, wv)
            const u8* wb = Wf + ((size_t)(L * 8 + wv) << 15) + (size_t)lane * 16;

            f32x4 acc[4];   // 0:tau ntp0, 1:tau ntp1, 2:forc ntp0, 3:forc ntp1
            #pragma unroll
            for (int n = 0; n < 4; ++n)
                acc[n] = (f32x4){0.f, 0.f, 0.f, 0.f};

            // K-step order: ci = 8..15 (h_prev half, pre-barrier), then 0..7.
            // depth-4 register prefetch of B pair-fragments (1 KB each).
            long2v bb[4][2];
            #pragma unroll
            for (int pi = 0; pi < 4; ++pi)
                #pragma unroll
                for (int g = 0; g < 2; ++g)
                    bb[pi][g] = *(const long2v*)(wb + (size_t)(((8 + pi) * 2 + g) << 10));

            #pragma unroll
            for (int s = 0; s < 16; ++s) {
                const int ci = (s < 8) ? (s + 8) : (s - 8);
                const int p = s & 3;
                if (s == 8) __syncthreads();   // sH[ws][L-1] now published
                const u8* Asrc = (s < 8) ? Ahi : Alo;   // static under unroll
                const int seg = (ci & 7) * 4 + quad;    // 8-B seg in [0,32)
                long a = *(const long*)&Asrc[l15 * 256 + (seg ^ l15) * 8];
                #pragma unroll
                for (int n = 0; n < 4; ++n)
                    acc[n] = __builtin_amdgcn_mfma_f32_16x16x32_fp8_fp8(
                        a, bb[p][n >> 1][n & 1], acc[n], 0, 0, 0);
                if (s + 4 < 16) {
                    const int nci = (s + 4 < 8) ? (s + 12) : (s - 4);
                    #pragma unroll
                    for (int g = 0; g < 2; ++g)
                        bb[p][g] = *(const long2v*)(wb + (size_t)((nci * 2 + g) << 10));
                }
            }

            // Epilogue. C/D: col = l15 (tile ntp), row = quad*4 + r.
            // Old h read from rs buffer; new h written to ws buffer. No
            // barrier after (next stage's mid-barrier protects readers).
            float dmax = 0.0f;
            #pragma unroll
            for (int ntp = 0; ntp < 2; ++ntp) {
                const int d = w32 + ntp * 16 + l15;
                const float2 b2 = sBias[L][d];
                const int seg = d >> 3, dlow = d & 7;
                #pragma unroll
                for (int r = 0; r < 4; ++r) {
                    float tpre = acc[ntp][r]     + b2.x;
                    float fpre = acc[ntp + 2][r] + b2.y;
                    tpre = fminf(30.f, fmaxf(-30.f, tpre));
                    fpre = fminf(15.f, fmaxf(-15.f, fpre));
                    // h/(sigma(t)+1e-6) == h*(1+u)/(1+eps+eps*u), u=e^-t
                    float u   = __expf(-tpre);
                    float den = 1.0f + 1e-6f + 1e-6f * u;
                    float rcp = __builtin_amdgcn_rcpf(den);
                    float e2  = __expf(2.0f * fpre);
                    float r2  = __builtin_amdgcn_rcpf(e2 + 1.0f);
                    float fo  = (e2 - 1.0f) * r2;
                    const int row = quad * 4 + r;
                    const int idx = row * 256 + (seg ^ row) * 8 + dlow;
                    float h  = fp8_to_f32(Ahi[idx]);
                    float gq = h * (1.0f + u) * rcp;
                    float nv = h + DT * (fo - gq);
                    nv = fminf(10.0f, fmaxf(-10.0f, nv));
                    Hout[idx] = f32_to_fp8(nv);
                    dmax = fmaxf(dmax, fabsf(nv - h));
                }
            }
            if (L == NLAYER - 1) {
                #pragma unroll
                for (int off = 32; off > 0; off >>= 1)
                    dmax = fmaxf(dmax, __shfl_xor(dmax, off));
                if (lane == 0)
                    atomicMax((unsigned int*)(deltas + t), __float_as_uint(dmax));
            }
        } // L
    } // t

    __syncthreads();   // all epilogue writes of t=TMAX-1 visible

    // ---- final output: layer-3 states from write-side of t=TMAX-1 ----
    {
        const u8* fin = &sH[((TMAX - 1) & 1) ^ 1][NLAYER - 1][0];
        int r = tid >> 5, seg = tid & 31;
        long v = *(const long*)&fin[r * 256 + (seg ^ r) * 8];
        int lo = (int)(v & 0xffffffffl);
        int hi = (int)(v >> 32);
        float* go = out + (rowbase + r) * HID + seg * 8;
        float4 o0, o1;
        o0.x = __builtin_amdgcn_cvt_f32_fp8(lo, 0);
        o0.y = __builtin_amdgcn_cvt_f32_fp8(lo, 1);
        o0.z = __builtin_amdgcn_cvt_f32_fp8(lo, 2);
        o0.w = __builtin_amdgcn_cvt_f32_fp8(lo, 3);
        o1.x = __builtin_amdgcn_cvt_f32_fp8(hi, 0);
        o1.y = __builtin_amdgcn_cvt_f32_fp8(hi, 1);
        o1.z = __builtin_amdgcn_cvt_f32_fp8(hi, 2);
        o1.w = __builtin_amdgcn_cvt_f32_fp8(hi, 3);
        *(float4*)go = o0;
        *(float4*)(go + 4) = o1;
    }
}

__global__ void result_kernel(const float* __restrict__ deltas,
                              float* __restrict__ out) {
    if (threadIdx.x == 0) {
        int res = TMAX;
        for (int t = 0; t < TMAX; ++t) {
            if (deltas[t] < EPSC) { res = t; break; }
        }
        out[(size_t)ROWS * HID] = (float)res;
    }
}

// ---------------------------------------------------------------------------
extern "C" void kernel_launch(void* const* d_in, const int* in_sizes, int n_in,
                              void* d_out, int out_size, void* d_ws, size_t ws_size,
                              hipStream_t stream) {
    const float* x  = (const float*)d_in[0];
    const float* Ws = (const float*)d_in[1];
    const float* bs = (const float*)d_in[2];
    const float* Wi = (const float*)d_in[3];
    const float* bi = (const float*)d_in[4];
    const float* Wt = (const float*)d_in[5];
    const float* bt = (const float*)d_in[6];
    float* out = (float*)d_out;

    char* p = (char*)d_ws;
    u8*    Wf     = (u8*)p;    p += (size_t)NLAYER * TWOH * TWOH;            // 1 MB
    float* bp     = (float*)p; p += (size_t)NLAYER * TWOH * sizeof(float);   // 8 KB
    float* deltas = (float*)p; p += 64 * sizeof(float);

    hipMemsetAsync(deltas, 0, 64 * sizeof(float), stream);
    pack_w_kernel<<<(NLAYER * TWOH * TWOH) / 256, 256, 0, stream>>>(Ws, Wi, Wt, Wf);
    pack_b_kernel<<<(NLAYER * TWOH) / 256, 256, 0, stream>>>(bs, bi, bt, bp);

    persistent_kernel<<<ROWS / BROW, 512, 0, stream>>>(x, Wf, bp, deltas, out);
    result_kernel<<<1, 64, 0, stream>>>(deltas, out);
}